// Round 6
// baseline (328.151 us; speedup 1.0000x reference)
//
#include <hip/hip_runtime.h>

// B=2048, N=64, D=256, H=16.
// out[b,n] = softmax_n( relu( ((N*u[b,n,:] - sum_n u) * item) @ W1 + b1 ) @ W2 )
// b2 dropped. y'[n,h] = (u[n,:]*item) @ W1[:,h]; z = 64*y' - sum_n y' + b1.
//
// R6: TLP experiment. Evidence: R0/R3 (different structures) both ~100 us at
// 8 waves/CU, all pipes <16%; R4/R5 pushed 3.5 TB/s of (mostly scratch)
// traffic at 12 waves/CU -> the memory system scales with outstanding
// requests, our clean kernels are TLP-starved. R6 doubles waves/CU to 16:
// block = 2 batches x 2 d-halves, one wave per (batch, d-half). acc halves
// (VGPR ~115 fits waves_per_eu(4,4) = 128 budget), LDS 35 KB -> 4 blocks/CU.
// Lane (n0,q) owns d-interleaved f4s (per-inst: 16 half-lines, R3 pattern).
// W1 xor-swizzled by (d>>2)&3 -> conflict-free 4-addr broadcast ds_reads.
// Item broadcast from LDS. R5-verified LDS-partial epilogue for the d-half
// combine. 2 barriers total, none in K-loop. Plain arrays only (r4 lesson);
// no global_load_lds with divergent LDS ptr (r5 lesson).

static constexpr int PSTRIDE = 68;   // partial row stride (floats)

#define FMA16(K, SV)                                                \
    acc[K][ 0] = fmaf(SV, wv0.x, acc[K][ 0]);                       \
    acc[K][ 1] = fmaf(SV, wv0.y, acc[K][ 1]);                       \
    acc[K][ 2] = fmaf(SV, wv0.z, acc[K][ 2]);                       \
    acc[K][ 3] = fmaf(SV, wv0.w, acc[K][ 3]);                       \
    acc[K][ 4] = fmaf(SV, wv1.x, acc[K][ 4]);                       \
    acc[K][ 5] = fmaf(SV, wv1.y, acc[K][ 5]);                       \
    acc[K][ 6] = fmaf(SV, wv1.z, acc[K][ 6]);                       \
    acc[K][ 7] = fmaf(SV, wv1.w, acc[K][ 7]);                       \
    acc[K][ 8] = fmaf(SV, wv2.x, acc[K][ 8]);                       \
    acc[K][ 9] = fmaf(SV, wv2.y, acc[K][ 9]);                       \
    acc[K][10] = fmaf(SV, wv2.z, acc[K][10]);                       \
    acc[K][11] = fmaf(SV, wv2.w, acc[K][11]);                       \
    acc[K][12] = fmaf(SV, wv3.x, acc[K][12]);                       \
    acc[K][13] = fmaf(SV, wv3.y, acc[K][13]);                       \
    acc[K][14] = fmaf(SV, wv3.z, acc[K][14]);                       \
    acc[K][15] = fmaf(SV, wv3.w, acc[K][15]);

// One chunk = 4 d per lane (one f4 per row). IOFF/DOFF are compile-time.
#define CHUNK(U0, U1, U2, U3, IOFF, DOFF)                           \
    do {                                                            \
        const float4 itv = pit[IOFF];                               \
        float s0[4] = {U0.x * itv.x, U0.y * itv.y, U0.z * itv.z, U0.w * itv.w}; \
        float s1[4] = {U1.x * itv.x, U1.y * itv.y, U1.z * itv.z, U1.w * itv.w}; \
        float s2[4] = {U2.x * itv.x, U2.y * itv.y, U2.z * itv.z, U2.w * itv.w}; \
        float s3[4] = {U3.x * itv.x, U3.y * itv.y, U3.z * itv.z, U3.w * itv.w}; \
        _Pragma("unroll")                                           \
        for (int e = 0; e < 4; ++e) {                               \
            const float4 wv0 = pw0[(DOFF) + 4 * e];                 \
            const float4 wv1 = pw1[(DOFF) + 4 * e];                 \
            const float4 wv2 = pw2[(DOFF) + 4 * e];                 \
            const float4 wv3 = pw3[(DOFF) + 4 * e];                 \
            FMA16(0, s0[e]) FMA16(1, s1[e])                         \
            FMA16(2, s2[e]) FMA16(3, s3[e])                         \
        }                                                           \
    } while (0)

__global__ __launch_bounds__(256) __attribute__((amdgpu_waves_per_eu(4, 4)))
void attn_group_softmax(const float* __restrict__ u_g,     // [B,64,256]
                        const float* __restrict__ item_g,  // [B,256]
                        const float* __restrict__ W1,      // [256,16]
                        const float* __restrict__ b1,      // [16]
                        const float* __restrict__ W2,      // [16,1]
                        float* __restrict__ out)           // [B,64]
{
    __shared__ __align__(16) float w1s[256 * 16];           // 16 KB, xor-swizzled
    __shared__ __align__(16) float item_s[2 * 256];         // 2 KB (2 batches)
    __shared__ __align__(16) float part[4 * 16 * PSTRIDE];  // 17.4 KB partials

    const int tid  = threadIdx.x;
    const int w    = tid >> 6;      // wave 0..3
    const int lane = tid & 63;
    const int bb   = w >> 1;        // batch within block (0,1)
    const int wh   = w & 1;         // d-half (0,1)
    const int b    = blockIdx.x * 2 + bb;

    // ---- stage W1 swizzled: row d, logical f4 c at slot c ^ ((d>>2)&3) ----
    {
        const int d = tid;
        const float4* src = (const float4*)(W1 + d * 16);
        float4* dst = (float4*)w1s + d * 4;
        const int sw = (d >> 2) & 3;
        #pragma unroll
        for (int c = 0; c < 4; ++c) dst[c ^ sw] = src[c];
    }
    // ---- stage item for both batches (2 KB) ----
    if (tid < 128) {
        const int bt = tid >> 6, ln = tid & 63;
        ((float4*)(item_s + bt * 256))[ln] =
            ((const float4*)(item_g + (size_t)(blockIdx.x * 2 + bt) * 256))[ln];
    }
    __syncthreads();

    const int q  = lane & 3;        // d-interleave selector
    const int n0 = lane >> 2;       // rows n0 + 16k

    const float4* ug4 = (const float4*)u_g + (size_t)b * 4096;
    // lane's f4 columns: 32*wh + 4*c' + q  (c' = 0..7) -> d = 128wh+16c'+4q+e
    const float4* pu0 = ug4 + (n0 +  0) * 64 + 32 * wh + q;
    const float4* pu1 = ug4 + (n0 + 16) * 64 + 32 * wh + q;
    const float4* pu2 = ug4 + (n0 + 32) * 64 + 32 * wh + q;
    const float4* pu3 = ug4 + (n0 + 48) * 64 + 32 * wh + q;
    const float4* pit = (const float4*)(item_s + bb * 256) + 32 * wh + q;
    // W1 pointers with xor-slot folded in (logical C -> slot C^q); row d of
    // chunk c', elem e lives at f4-index (128wh+4q)*4 + 64c' + 4e + (C^q).
    const float4* pwb = (const float4*)w1s + (128 * wh + 4 * q) * 4;
    const float4* pw0 = pwb + (0 ^ q);
    const float4* pw1 = pwb + (1 ^ q);
    const float4* pw2 = pwb + (2 ^ q);
    const float4* pw3 = pwb + (3 ^ q);

    float acc[4][16];
    #pragma unroll
    for (int k = 0; k < 4; ++k)
        #pragma unroll
        for (int h = 0; h < 16; ++h) acc[k][h] = 0.f;

    // double-buffered: chunk pair per iteration, all offsets immediate
    float4 A0 = pu0[0], A1 = pu1[0], A2 = pu2[0], A3 = pu3[0];

    #pragma unroll 1
    for (int p = 0; p < 4; ++p) {
        float4 B0 = pu0[4], B1 = pu1[4], B2 = pu2[4], B3 = pu3[4];
        CHUNK(A0, A1, A2, A3, 0, 0);
        if (p < 3) { A0 = pu0[8]; A1 = pu1[8]; A2 = pu2[8]; A3 = pu3[8]; }
        CHUNK(B0, B1, B2, B3, 4, 64);
        pu0 += 8; pu1 += 8; pu2 += 8; pu3 += 8; pit += 8;
        pw0 += 128; pw1 += 128; pw2 += 128; pw3 += 128;
    }

    // ---- reduce q-partials in-wave (xor 1,2): wave's d-half y' ----
    #pragma unroll
    for (int k = 0; k < 4; ++k)
        #pragma unroll
        for (int h = 0; h < 16; ++h) {
            float v = acc[k][h];
            v += __shfl_xor(v, 1, 64);
            v += __shfl_xor(v, 2, 64);
            acc[k][h] = v;
        }

    // ---- write per-wave partials to LDS ----
    if (q == 0) {
        float* pb = part + (w * 16 + n0) * PSTRIDE;
        #pragma unroll
        for (int k = 0; k < 4; ++k)
            #pragma unroll
            for (int c = 0; c < 4; ++c)
                *(float4*)(pb + k * 16 + c * 4) =
                    make_float4(acc[k][4*c+0], acc[k][4*c+1], acc[k][4*c+2], acc[k][4*c+3]);
    }
    __syncthreads();

    if (wh != 0) return;   // waves 0 and 2 finish batches 0 and 1

    // ---- combine the 2 d-halves (reuse acc as the full y') ----
    #pragma unroll
    for (int k = 0; k < 4; ++k)
        #pragma unroll
        for (int c = 0; c < 4; ++c) {
            const float4 pa = *(const float4*)(part + ((2 * bb + 0) * 16 + n0) * PSTRIDE + k * 16 + c * 4);
            const float4 pbv= *(const float4*)(part + ((2 * bb + 1) * 16 + n0) * PSTRIDE + k * 16 + c * 4);
            acc[k][4*c+0] = pa.x + pbv.x;
            acc[k][4*c+1] = pa.y + pbv.y;
            acc[k][4*c+2] = pa.z + pbv.z;
            acc[k][4*c+3] = pa.w + pbv.w;
        }

    // ---- tt[h] = sum over all 64 members ----
    float tt[16];
    #pragma unroll
    for (int h = 0; h < 16; ++h) {
        float s = acc[0][h] + acc[1][h] + acc[2][h] + acc[3][h];
        #pragma unroll
        for (int off = 4; off <= 32; off <<= 1) s += __shfl_xor(s, off, 64);
        tt[h] = s;
    }

    // ---- b1 / W2 ----
    float b1c[16], w2c[16];
    {
        const float4* b4 = (const float4*)b1;
        const float4* w4 = (const float4*)W2;
        #pragma unroll
        for (int c = 0; c < 4; ++c) {
            const float4 t1 = b4[c], t2 = w4[c];
            b1c[4*c+0] = t1.x; b1c[4*c+1] = t1.y; b1c[4*c+2] = t1.z; b1c[4*c+3] = t1.w;
            w2c[4*c+0] = t2.x; w2c[4*c+1] = t2.y; w2c[4*c+2] = t2.z; w2c[4*c+3] = t2.w;
        }
    }

    // ---- logits: z = 64*y' - tt + b1, relu, dot W2 ----
    float p[4];
    #pragma unroll
    for (int k = 0; k < 4; ++k) {
        float sum = 0.f;
        #pragma unroll
        for (int h = 0; h < 16; ++h) {
            float z = fmaf(64.f, acc[k][h], b1c[h] - tt[h]);
            z = fmaxf(z, 0.f);
            sum = fmaf(z, w2c[h], sum);
        }
        p[k] = sum;
    }

    // ---- softmax over 64 members (16 n0-lanes x 4 rows, q-replicated) ----
    float m = fmaxf(fmaxf(p[0], p[1]), fmaxf(p[2], p[3]));
    #pragma unroll
    for (int off = 4; off <= 32; off <<= 1) m = fmaxf(m, __shfl_xor(m, off, 64));
    const float e0 = __expf(p[0] - m);
    const float e1 = __expf(p[1] - m);
    const float e2 = __expf(p[2] - m);
    const float e3 = __expf(p[3] - m);
    float sden = e0 + e1 + e2 + e3;
    #pragma unroll
    for (int off = 4; off <= 32; off <<= 1) sden += __shfl_xor(sden, off, 64);
    const float inv = 1.0f / sden;

    if (q == 0) {
        float* ob = out + (size_t)b * 64 + n0;
        ob[0]  = e0 * inv;
        ob[16] = e1 * inv;
        ob[32] = e2 * inv;
        ob[48] = e3 * inv;
    }
}

extern "C" void kernel_launch(void* const* d_in, const int* in_sizes, int n_in,
                              void* d_out, int out_size, void* d_ws, size_t ws_size,
                              hipStream_t stream) {
    const float* u    = (const float*)d_in[0];  // members_embeds [2048,64,256]
    const float* item = (const float*)d_in[1];  // item_embeds   [2048,256]
    const float* W1   = (const float*)d_in[2];  // [256,16]
    const float* b1   = (const float*)d_in[3];  // [16]
    const float* W2   = (const float*)d_in[4];  // [16,1]
    // d_in[5] = b2: dropped (softmax shift-invariant)
    (void)in_sizes; (void)n_in; (void)out_size; (void)d_ws; (void)ws_size;

    attn_group_softmax<<<1024, 256, 0, stream>>>(u, item, W1, b1, W2, (float*)d_out);
}